// Round 1
// baseline (381.856 us; speedup 1.0000x reference)
//
#include <hip/hip_runtime.h>
#include <stdint.h>

#define Bdim 32
#define Cdim 512
#define Ndim 4096
#define Kdim 32
#define NPX 32          // pixels per chunk
#define NCH 16          // chunks per block (512 px window)
#define PWIN 8          // px-windows per image; grid k1 = Bdim*PWIN = 256

// ws: part[256][K][C] f32 (16 MiB) | wsum_part[256][K] | c2[K]
static constexpr size_t WS_WSUM_OFF = (size_t)256 * Kdim * Cdim * 4;          // 16777216
static constexpr size_t WS_C2_OFF   = WS_WSUM_OFF + (size_t)256 * Kdim * 4;   // +32768

using bf16x8 = __attribute__((ext_vector_type(8))) short;
using f32x4  = __attribute__((ext_vector_type(4))) float;

static __device__ __forceinline__ unsigned short f2bf(float f) {
    unsigned int u = __float_as_uint(f);
    u += 0x7fffu + ((u >> 16) & 1u);
    return (unsigned short)(u >> 16);
}

// ---------------------------------------------------------------------------
// K0: c2[k] = sum_c cw[k][c]^2
// ---------------------------------------------------------------------------
__global__ __launch_bounds__(256) void k0_c2(const float* __restrict__ cw,
                                             float* __restrict__ c2) {
    __shared__ float partl[8][32];
    int t = threadIdx.x;
    int k = t & 31, g = t >> 5;
    float s = 0.f;
    int c0 = g * 64;
    for (int c = c0; c < c0 + 64; ++c) {
        float v = cw[k * Cdim + c];
        s += v * v;
    }
    partl[g][k] = s;
    __syncthreads();
    if (t < 32) {
        float tot = 0.f;
        #pragma unroll
        for (int gg = 0; gg < 8; ++gg) tot += partl[gg][t];
        c2[t] = tot;
    }
}

// ---------------------------------------------------------------------------
// K1: fused, MFMA both passes. 256 blocks x 512 threads (1 blk/CU, 2 w/SIMD).
// ---------------------------------------------------------------------------
__global__ __launch_bounds__(512, 2) void k1_fused(const float* __restrict__ x,
                                                   const float* __restrict__ cw,
                                                   const float* __restrict__ scale,
                                                   const float* __restrict__ c2g,
                                                   float* __restrict__ part,
                                                   float* __restrict__ wsum_part) {
    __shared__ unsigned short cw_s[Kdim][520];    // [k][c] bf16, pass1-B
    __shared__ unsigned short x_n[NPX][520];      // [px][c] bf16, pass1-A
    __shared__ unsigned short x_t[Cdim][40];      // [c][px] bf16, pass2-B
    __shared__ float          S_s[2][NPX][36];    // raw dots, c-halves
    __shared__ unsigned short w_t[Kdim][40];      // [k][px] bf16, pass2-A
    __shared__ float          x2_w[8][NPX];       // per-wave x2 partials
    __shared__ float          wsum_w[4][Kdim];    // per-wave wsum partials

    const int t    = threadIdx.x;
    const int blk  = blockIdx.x;
    const int b    = blk >> 3;
    const int pw   = blk & 7;
    const int lane = t & 63;
    const int lr   = lane & 15;
    const int lq   = lane >> 4;
    const int wv   = t >> 6;        // wave 0..7
    // staging ids: px-pair pp, c-row-group crg
    const int pp   = t & 15;        // px = 2pp, 2pp+1
    const int crg  = t >> 4;        // 0..31 -> c = 2crg + 64i (pairs c,c+1)
    // softmax ids (t < 256)
    const int q    = t & 7;         // k-quad
    const int px   = t >> 3;        // 0..31
    // pass-1 wave roles
    const int pt   = wv & 1;        // px half
    const int kt2  = (wv >> 1) & 1; // k half
    const int ch   = wv >> 2;       // c half

    // one-time: cw -> bf16 LDS (512 threads, 8 float4 each)
    #pragma unroll
    for (int i = 0; i < 8; ++i) {
        int f4 = t + 512 * i;              // over [32 k][128 c4]
        int k  = f4 >> 7;
        int c4 = (f4 & 127) * 4;
        float4 v = *(const float4*)(cw + (size_t)k * Cdim + c4);
        ushort4 u;
        u.x = f2bf(v.x); u.y = f2bf(v.y); u.z = f2bf(v.z); u.w = f2bf(v.w);
        *(ushort4*)&cw_s[k][c4] = u;
    }

    float4 sc4, c24;
    if (t < 256) {
        sc4 = *(const float4*)(scale + 4 * q);
        c24 = *(const float4*)(c2g + 4 * q);
    }

    const float* xb = x + (size_t)b * Cdim * Ndim;

    // prefetch chunk 0: thread covers c pairs {2crg+64i, +1}, px pair 2pp
    float2 pa[8], pb[8];
    {
        int n0 = pw * 512;
        #pragma unroll
        for (int i = 0; i < 8; ++i) {
            int c = 2 * crg + 64 * i;
            pa[i] = *(const float2*)(xb + (size_t)c * Ndim + n0 + 2 * pp);
            pb[i] = *(const float2*)(xb + (size_t)(c + 1) * Ndim + n0 + 2 * pp);
        }
    }

    f32x4 acc[2][4];                 // [k-half][c-tile] ; wave owns 64 c
    #pragma unroll
    for (int kt = 0; kt < 2; ++kt)
        #pragma unroll
        for (int ct = 0; ct < 4; ++ct) acc[kt][ct] = (f32x4){0.f, 0.f, 0.f, 0.f};
    float wsum_r[4] = {0.f, 0.f, 0.f, 0.f};   // valid for t<256

    __syncthreads();   // cw staging done

    for (int ci = 0; ci < NCH; ++ci) {
        // ---------------- stage x from prefetch regs ----------------
        float x2p0 = 0.f, x2p1 = 0.f;
        #pragma unroll
        for (int i = 0; i < 8; ++i) {
            int c = 2 * crg + 64 * i;
            float2 a = pa[i], bb = pb[i];
            unsigned short ax = f2bf(a.x), ay = f2bf(a.y);
            unsigned short bx = f2bf(bb.x), by = f2bf(bb.y);
            ushort2 u;
            u.x = ax; u.y = ay; *(ushort2*)&x_t[c][2 * pp] = u;       // [c][px]
            u.x = bx; u.y = by; *(ushort2*)&x_t[c + 1][2 * pp] = u;
            u.x = ax; u.y = bx; *(ushort2*)&x_n[2 * pp][c] = u;       // [px][c]
            u.x = ay; u.y = by; *(ushort2*)&x_n[2 * pp + 1][c] = u;
            x2p0 += a.x * a.x + bb.x * bb.x;
            x2p1 += a.y * a.y + bb.y * bb.y;
        }
        // per-wave x2 partials: collapse crg within wave (lanes xor 16,32)
        x2p0 += __shfl_xor(x2p0, 16); x2p1 += __shfl_xor(x2p1, 16);
        x2p0 += __shfl_xor(x2p0, 32); x2p1 += __shfl_xor(x2p1, 32);
        if (lane < 16) {
            float2 v; v.x = x2p0; v.y = x2p1;
            *(float2*)&x2_w[wv][2 * pp] = v;
        }
        // prefetch next chunk (overlaps pass1/softmax/pass2)
        if (ci + 1 < NCH) {
            int nn = pw * 512 + (ci + 1) * 32;
            #pragma unroll
            for (int i = 0; i < 8; ++i) {
                int c = 2 * crg + 64 * i;
                pa[i] = *(const float2*)(xb + (size_t)c * Ndim + nn + 2 * pp);
                pb[i] = *(const float2*)(xb + (size_t)(c + 1) * Ndim + nn + 2 * pp);
            }
        }
        __syncthreads();

        // ---------------- pass 1: dots via MFMA (c split across wave pairs) ----
        {
            f32x4 d = (f32x4){0.f, 0.f, 0.f, 0.f};
            #pragma unroll
            for (int s = 0; s < 8; ++s) {
                int col = 256 * ch + 32 * s + 8 * lq;
                bf16x8 av = *(const bf16x8*)&x_n[16 * pt + lr][col];
                bf16x8 bv = *(const bf16x8*)&cw_s[16 * kt2 + lr][col];
                d = __builtin_amdgcn_mfma_f32_16x16x32_bf16(av, bv, d, 0, 0, 0);
            }
            #pragma unroll
            for (int r = 0; r < 4; ++r)
                S_s[ch][16 * pt + 4 * lq + r][16 * kt2 + lr] = d[r];
        }
        __syncthreads();

        // ---------------- softmax (t<256: px = t>>3, k-quad q) ----------------
        if (t < 256) {
            float4 dv0 = *(const float4*)&S_s[0][px][4 * q];
            float4 dv1 = *(const float4*)&S_s[1][px][4 * q];
            float xx = 0.f;
            #pragma unroll
            for (int w = 0; w < 8; ++w) xx += x2_w[w][px];
            float d0 = sc4.x * (xx - 2.f * (dv0.x + dv1.x) + c24.x);
            float d1 = sc4.y * (xx - 2.f * (dv0.y + dv1.y) + c24.y);
            float d2 = sc4.z * (xx - 2.f * (dv0.z + dv1.z) + c24.z);
            float d3 = sc4.w * (xx - 2.f * (dv0.w + dv1.w) + c24.w);
            float m = fmaxf(fmaxf(d0, d1), fmaxf(d2, d3));
            m = fmaxf(m, __shfl_xor(m, 1));
            m = fmaxf(m, __shfl_xor(m, 2));
            m = fmaxf(m, __shfl_xor(m, 4));
            float e0 = __expf(d0 - m), e1 = __expf(d1 - m);
            float e2 = __expf(d2 - m), e3 = __expf(d3 - m);
            float ss = e0 + e1 + e2 + e3;
            ss += __shfl_xor(ss, 1);
            ss += __shfl_xor(ss, 2);
            ss += __shfl_xor(ss, 4);
            float inv = 1.f / ss;
            float w0 = e0 * inv, w1 = e1 * inv, w2 = e2 * inv, w3 = e3 * inv;
            wsum_r[0] += w0; wsum_r[1] += w1; wsum_r[2] += w2; wsum_r[3] += w3;
            w_t[4 * q + 0][px] = f2bf(w0);
            w_t[4 * q + 1][px] = f2bf(w1);
            w_t[4 * q + 2][px] = f2bf(w2);
            w_t[4 * q + 3][px] = f2bf(w3);
        }
        __syncthreads();

        // ---------------- pass 2: out-tile MFMA, wave owns 64 c ----------------
        {
            bf16x8 a0 = *(const bf16x8*)&w_t[lr][8 * lq];
            bf16x8 a1 = *(const bf16x8*)&w_t[16 + lr][8 * lq];
            #pragma unroll
            for (int ct = 0; ct < 4; ++ct) {
                bf16x8 bv = *(const bf16x8*)&x_t[64 * wv + 16 * ct + lr][8 * lq];
                acc[0][ct] = __builtin_amdgcn_mfma_f32_16x16x32_bf16(a0, bv, acc[0][ct], 0, 0, 0);
                acc[1][ct] = __builtin_amdgcn_mfma_f32_16x16x32_bf16(a1, bv, acc[1][ct], 0, 0, 0);
            }
        }
        __syncthreads();   // x_t/x_n/w_t reusable next chunk
    }

    // ---------------- epilogue ----------------
    // wsum: collapse px within each of waves 0..3, then cross-wave sum
    if (t < 256) {
        #pragma unroll
        for (int j = 0; j < 4; ++j) {
            float v = wsum_r[j];
            v += __shfl_xor(v, 8);
            v += __shfl_xor(v, 16);
            v += __shfl_xor(v, 32);
            if (lane < 8) wsum_w[wv][4 * lane + j] = v;
        }
    }
    {
        float* pbuf = part + (size_t)blk * (Kdim * Cdim);
        #pragma unroll
        for (int kt = 0; kt < 2; ++kt)
            #pragma unroll
            for (int ct = 0; ct < 4; ++ct)
                #pragma unroll
                for (int r = 0; r < 4; ++r)
                    pbuf[(size_t)(16 * kt + 4 * lq + r) * Cdim + 64 * wv + 16 * ct + lr] =
                        acc[kt][ct][r];
    }
    __syncthreads();
    if (t < 32) {
        float s = wsum_w[0][t] + wsum_w[1][t] + wsum_w[2][t] + wsum_w[3][t];
        wsum_part[blk * Kdim + t] = s;
    }
}

// ---------------------------------------------------------------------------
// K2: reduce 8 partials per (b,k) + subtract wsum*cw.
// ---------------------------------------------------------------------------
__global__ __launch_bounds__(256) void k2_reduce(const float* __restrict__ part,
                                                 const float* __restrict__ wsum_part,
                                                 const float* __restrict__ cw,
                                                 float* __restrict__ out) {
    int blk = blockIdx.x;
    int b = blk >> 5, k = blk & 31;
    int t = threadIdx.x;
    float ws = 0.f;
    #pragma unroll
    for (int p = 0; p < PWIN; ++p) ws += wsum_part[(b * PWIN + p) * Kdim + k];
    int c = 2 * t;
    float sx = 0.f, sy = 0.f;
    #pragma unroll
    for (int p = 0; p < PWIN; ++p) {
        const float2 v = *(const float2*)(part + ((size_t)(b * PWIN + p) * Kdim + k) * Cdim + c);
        sx += v.x;
        sy += v.y;
    }
    float2 cv = *(const float2*)(cw + (size_t)k * Cdim + c);
    float2 o;
    o.x = sx - ws * cv.x;
    o.y = sy - ws * cv.y;
    *(float2*)(out + ((size_t)b * Kdim + k) * Cdim + c) = o;
}

// ---------------------------------------------------------------------------
extern "C" void kernel_launch(void* const* d_in, const int* in_sizes, int n_in,
                              void* d_out, int out_size, void* d_ws, size_t ws_size,
                              hipStream_t stream) {
    const float* x     = (const float*)d_in[0];   // [B][C][N]
    const float* cw    = (const float*)d_in[1];   // [K][C]
    const float* scale = (const float*)d_in[2];   // [K]
    float* out = (float*)d_out;                   // [B][K][C]

    char* wsb = (char*)d_ws;
    float* part      = (float*)wsb;
    float* wsum_part = (float*)(wsb + WS_WSUM_OFF);
    float* c2        = (float*)(wsb + WS_C2_OFF);

    k0_c2<<<1, 256, 0, stream>>>(cw, c2);
    k1_fused<<<Bdim * PWIN, 512, 0, stream>>>(x, cw, scale, c2, part, wsum_part);
    k2_reduce<<<Bdim * Kdim, 256, 0, stream>>>(part, wsum_part, cw, out);
}